// Round 14
// baseline (531.266 us; speedup 1.0000x reference)
//
#include <hip/hip_runtime.h>
#include <stdint.h>

typedef unsigned short u16;
typedef __attribute__((ext_vector_type(8))) __bf16 bf16x8;
typedef __attribute__((ext_vector_type(4))) float f32x4;

#define SEQL 2048
#define NHEADS 16
#define HDIM 64
#define BSZ 4
#define EMB 1024
#define MROWS (BSZ * SEQL) /* 8192 */
#define LOG2E 1.44269504088896f
#define NKT 32 /* K tiles of 32 over K=1024 */

__device__ __forceinline__ u16 f2bf(float f) {
  union { float f; uint32_t u; } v; v.f = f;
  return (u16)((v.u + 0x7fffu + ((v.u >> 16) & 1u)) >> 16);
}

__device__ __forceinline__ void g2l(const u16* g, u16* l) {
  __builtin_amdgcn_global_load_lds(
      (__attribute__((address_space(1))) void*)(g),
      (__attribute__((address_space(3))) void*)(l), 16, 0, 0);
}

__device__ __forceinline__ void cvt8(const float* __restrict__ in, u16* __restrict__ out, int i) {
  float4 a = *(const float4*)(in + i);
  float4 b = *(const float4*)(in + i + 4);
  uint4 o;
  o.x = f2bf(a.x) | ((uint32_t)f2bf(a.y) << 16);
  o.y = f2bf(a.z) | ((uint32_t)f2bf(a.w) << 16);
  o.z = f2bf(b.x) | ((uint32_t)f2bf(b.y) << 16);
  o.w = f2bf(b.z) | ((uint32_t)f2bf(b.w) << 16);
  *(uint4*)(out + i) = o;
}

// ---------------- fused fp32 -> bf16 conversion (X + all 4 weights) ----------------
#define XN (MROWS * EMB)
__global__ void cvt_all(const float* __restrict__ query,
                        const float* __restrict__ w0, const float* __restrict__ w1,
                        const float* __restrict__ w2, const float* __restrict__ w3,
                        u16* __restrict__ Xb, u16* __restrict__ Wqb) {
  int i = (blockIdx.x * blockDim.x + threadIdx.x) * 8;
  if (i < XN) {
    cvt8(query, Xb, i);
  } else {
    int j = i - XN;
    int w = j >> 20;
    int jj = j & 1048575;
    const float* src = w == 0 ? w0 : w == 1 ? w1 : w == 2 ? w2 : w3;
    cvt8(src, Wqb + ((size_t)w << 20), jj);
  }
}

// ============ GEMM core: C[128x256] = A[128xK] * B[256xK]^T, K=1024 ==============
// Shared fragment/MFMA tail used by both ring depths.
#define GFRAGS_MFMA(RBASE)                                                          \
  {                                                                                 \
    const u16* Ab = (RBASE);                                                        \
    const u16* Bb = Ab + 4096;                                                      \
    bf16x8 af[4], bfr[4];                                                           \
    _Pragma("unroll") for (int i = 0; i < 4; ++i) {                                 \
      af[i] = *(const bf16x8*)(Ab + (wr * 64 + i * 16 + lrow) * 32 + kg);           \
      bfr[i] = *(const bf16x8*)(Bb + (wc * 64 + i * 16 + lrow) * 32 + kg);          \
    }                                                                               \
    __builtin_amdgcn_s_setprio(1);                                                  \
    _Pragma("unroll") for (int mi = 0; mi < 4; ++mi)                                \
      _Pragma("unroll") for (int ni = 0; ni < 4; ++ni)                              \
        acc[mi][ni] =                                                               \
            __builtin_amdgcn_mfma_f32_16x16x32_bf16(af[mi], bfr[ni], acc[mi][ni],   \
                                                    0, 0, 0);                       \
    __builtin_amdgcn_s_setprio(0);                                                  \
  }

#define GBODY3(WSTR, RBUF, DOPF, PFT, WBUF)                                         \
  {                                                                                 \
    asm volatile("s_waitcnt " WSTR ::: "memory");                                   \
    __builtin_amdgcn_sched_barrier(0);                                              \
    __builtin_amdgcn_s_barrier();                                                   \
    __builtin_amdgcn_sched_barrier(0);                                              \
    if (DOPF) {                                                                     \
      u16* d = lds + (WBUF) * 12288;                                                \
      g2l(Agb + (PFT) * 32, d + tid * 8);                                           \
      g2l(Bgb0 + (PFT) * 32, d + 4096 + tid * 8);                                   \
      g2l(Bgb1 + (PFT) * 32, d + 8192 + tid * 8);                                   \
    }                                                                               \
    GFRAGS_MFMA(lds + (RBUF) * 12288)                                               \
  }

// depth-3 ring (72 KB): counted vmcnt(3), 2-iteration prefetch distance (R8 proven)
__device__ __forceinline__ void gemm_core256(const u16* __restrict__ A,
                                             const u16* __restrict__ B,
                                             int m0, int n0, u16* lds,
                                             f32x4 acc[4][4]) {
  const int tid = threadIdx.x;
  const int lane = tid & 63, wid = tid >> 6;
  const int wr = wid >> 2, wc = wid & 3;
  const int lrow = lane & 15, kg = (lane >> 4) * 8;
  const int srow = tid >> 2, scolE = (tid & 3) * 8;

  const u16* Agb  = A + (size_t)(m0 + srow) * EMB + scolE;
  const u16* Bgb0 = B + (size_t)(n0 + srow) * EMB + scolE;
  const u16* Bgb1 = B + (size_t)(n0 + 128 + srow) * EMB + scolE;

#pragma unroll
  for (int t = 0; t < 2; ++t) {
    u16* d = lds + t * 12288;
    g2l(Agb + t * 32, d + tid * 8);
    g2l(Bgb0 + t * 32, d + 4096 + tid * 8);
    g2l(Bgb1 + t * 32, d + 8192 + tid * 8);
  }

  int rb = 0;
#pragma unroll 1
  for (int kt = 0; kt < NKT - 2; ++kt) {
    int wb = rb + 2; if (wb >= 3) wb -= 3;
    GBODY3("vmcnt(3)", rb, true, kt + 2, wb)
    ++rb; if (rb == 3) rb = 0;
  }
  GBODY3("vmcnt(3)", rb, false, 0, 0)
  { int rb2 = rb + 1; if (rb2 == 3) rb2 = 0;
    GBODY3("vmcnt(0)", rb2, false, 0, 0) }
}

// depth-2 ring (48 KB -> 3 blocks/CU at 512 thr): one-iteration prefetch distance.
// Iter kt: wait own loads (issued at kt-1, a full compute-iter of cover), barrier,
// issue kt+1 into buf[(kt+1)&1] (read during kt-1, all reads done pre-barrier).
__device__ __forceinline__ void gemm_core256_d2(const u16* __restrict__ A,
                                                const u16* __restrict__ B,
                                                int m0, int n0, u16* lds,
                                                f32x4 acc[4][4]) {
  const int tid = threadIdx.x;
  const int lane = tid & 63, wid = tid >> 6;
  const int wr = wid >> 2, wc = wid & 3;
  const int lrow = lane & 15, kg = (lane >> 4) * 8;
  const int srow = tid >> 2, scolE = (tid & 3) * 8;

  const u16* Agb  = A + (size_t)(m0 + srow) * EMB + scolE;
  const u16* Bgb0 = B + (size_t)(n0 + srow) * EMB + scolE;
  const u16* Bgb1 = B + (size_t)(n0 + 128 + srow) * EMB + scolE;

  // prologue: stage kt0 into buf0
  g2l(Agb, lds + tid * 8);
  g2l(Bgb0, lds + 4096 + tid * 8);
  g2l(Bgb1, lds + 8192 + tid * 8);

#pragma unroll 1
  for (int kt = 0; kt < NKT; ++kt) {
    asm volatile("s_waitcnt vmcnt(0)" ::: "memory");
    __builtin_amdgcn_sched_barrier(0);
    __builtin_amdgcn_s_barrier();
    __builtin_amdgcn_sched_barrier(0);
    if (kt + 1 < NKT) {
      u16* d = lds + ((kt + 1) & 1) * 12288;
      g2l(Agb + (kt + 1) * 32, d + tid * 8);
      g2l(Bgb0 + (kt + 1) * 32, d + 4096 + tid * 8);
      g2l(Bgb1 + (kt + 1) * 32, d + 8192 + tid * 8);
    }
    GFRAGS_MFMA(lds + (kt & 1) * 12288)
  }
}

// Fused QKV projection. depth-2 ring, grid 768 = exactly 3 blocks/CU resident.
__global__ __launch_bounds__(512, 6) void gemm_qkv3(
    const u16* __restrict__ X, const u16* __restrict__ Wcat,
    const float* __restrict__ bq, const float* __restrict__ bk, const float* __restrict__ bv,
    u16* __restrict__ Qb, u16* __restrict__ Kb, u16* __restrict__ Vt) {
  __shared__ u16 lds[2 * 12288];
  const int orig = blockIdx.x;
  const int virt = (orig & 7) * 96 + (orig >> 3);
  const int mt = virt / 12, nt = virt % 12;

  const f32x4 fzero = {0.f, 0.f, 0.f, 0.f};
  f32x4 acc[4][4];
#pragma unroll
  for (int i = 0; i < 4; ++i)
#pragma unroll
    for (int j = 0; j < 4; ++j) acc[i][j] = fzero;

  gemm_core256_d2(X, Wcat, mt * 128, nt * 256, lds, acc);

  const int tid = threadIdx.x, lane = tid & 63, wid = tid >> 6;
  const int wr = wid >> 2, wc = wid & 3;
  const int lrow = lane & 15, g = lane >> 4;
  const int which = nt >> 2;
  const float* bias = which == 0 ? bq : which == 1 ? bk : bv;
  const float scale = which == 0 ? 0.125f * LOG2E : 1.0f;

  if (which == 2) {
#pragma unroll
    for (int mi = 0; mi < 4; ++mi)
#pragma unroll
      for (int ni = 0; ni < 4; ++ni) {
        int n = nt * 256 + wc * 64 + ni * 16 + lrow;
        int nn = n & 1023;
        float bs = bias[nn];
        int h = nn >> 6, d = nn & 63;
        int m0r = mt * 128 + wr * 64 + mi * 16 + g * 4;
        int b = m0r >> 11, s = m0r & 2047;
        union { u16 s4[4]; uint2 u; } o;
#pragma unroll
        for (int r = 0; r < 4; ++r) o.s4[r] = f2bf(acc[mi][ni][r] + bs);
        *(uint2*)(Vt + ((size_t)(b * NHEADS + h) * HDIM + d) * SEQL + s) = o.u;
      }
  } else {
    u16* Ob = which == 0 ? Qb : Kb;
#pragma unroll
    for (int mi = 0; mi < 4; ++mi)
#pragma unroll
      for (int ni = 0; ni < 4; ++ni) {
        int n = nt * 256 + wc * 64 + ni * 16 + lrow;
        int nn = n & 1023;
        float bs = bias[nn];
        int h = nn >> 6, d = nn & 63;
#pragma unroll
        for (int r = 0; r < 4; ++r) {
          int m = mt * 128 + wr * 64 + mi * 16 + g * 4 + r;
          int b = m >> 11, s = m & 2047;
          float v = (acc[mi][ni][r] + bs) * scale;
          Ob[(size_t)((b * NHEADS + h) * SEQL + s) * HDIM + d] = f2bf(v);
        }
      }
  }
}

// Output projection (R8 proven, depth-3). Grid 256.
__global__ __launch_bounds__(512, 4) void gemm_out2(
    const u16* __restrict__ Ain, const u16* __restrict__ Wo,
    const float* __restrict__ bo, float* __restrict__ out) {
  __shared__ u16 lds[3 * 12288];
  const int orig = blockIdx.x;
  const int virt = (orig & 7) * 32 + (orig >> 3);
  const int mt = virt >> 2, nt = virt & 3;

  const f32x4 fzero = {0.f, 0.f, 0.f, 0.f};
  f32x4 acc[4][4];
#pragma unroll
  for (int i = 0; i < 4; ++i)
#pragma unroll
    for (int j = 0; j < 4; ++j) acc[i][j] = fzero;

  gemm_core256(Ain, Wo, mt * 128, nt * 256, lds, acc);

  const int tid = threadIdx.x, lane = tid & 63, wid = tid >> 6;
  const int wr = wid >> 2, wc = wid & 3;
  const int lrow = lane & 15, g = lane >> 4;
#pragma unroll
  for (int mi = 0; mi < 4; ++mi)
#pragma unroll
    for (int ni = 0; ni < 4; ++ni) {
      int n = nt * 256 + wc * 64 + ni * 16 + lrow;
      float bs = bo[n];
#pragma unroll
      for (int r = 0; r < 4; ++r) {
        int m = mt * 128 + wr * 64 + mi * 16 + g * 4 + r;
        out[(size_t)m * EMB + n] = acc[mi][ni][r] + bs;
      }
    }
}

// ---------------- causal flash attention (R11's proven attn6, 74.9 us) -----------
// QBLK=128, 512 threads, shared K/V staging, pair-balanced {qa, 15-qa} -> 34
// uniform KV-iters/block, grid 512.
__device__ __forceinline__ int swz(int row, int colE) {
  return row * 64 + (colE ^ ((row & 7) << 3));
}

__global__ __launch_bounds__(512, 4) void attn6_kernel(
    const u16* __restrict__ Qb, const u16* __restrict__ Kb, const u16* __restrict__ Vt,
    u16* __restrict__ Ab) {
  __shared__ u16 Ks[2][64 * 64];
  __shared__ u16 Vs[2][64 * 64];

  const int bid = blockIdx.x;
  const int qa  = bid >> 6;          // 0..7
  const int bh  = bid & 63;

  const int tid = threadIdx.x, lane = tid & 63, wid = tid >> 6;  // wid 0..7
  const int lrow = lane & 15, g = lane >> 4, kg = g * 8;

  const u16* Qbh = Qb + (size_t)bh * SEQL * HDIM;
  const u16* Kbh = Kb + (size_t)bh * SEQL * HDIM;
  const u16* Vbh = Vt + (size_t)bh * HDIM * SEQL;

  const int srow = tid >> 3;            // 0..63 (full tile, one load/thread)
  const int sce  = (tid & 7) * 8;

  const f32x4 fzero = {0.f, 0.f, 0.f, 0.f};
  const int b = bh >> 4, h = bh & 15;

#pragma unroll 1
  for (int ph = 0; ph < 2; ++ph) {
    const int qt = ph ? (15 - qa) : qa;      // q-tile of 128 rows
    const int q0 = qt * 128;
    const int NT = 2 * (qt + 1);             // 64-wide kv tiles

    const int qrow = q0 + wid * 16 + lrow;
    const bf16x8 qf0 = *(const bf16x8*)(Qbh + (size_t)qrow * HDIM + kg);
    const bf16x8 qf1 = *(const bf16x8*)(Qbh + (size_t)qrow * HDIM + 32 + kg);

    float m_run = -1e30f, l_run = 0.f;
    f32x4 accO[4];
#pragma unroll
    for (int d = 0; d < 4; ++d) accO[d] = fzero;

    // prologue: stage tile 0 (1 K + 1 V uint4 per thread)
    {
      uint4 k0 = *(const uint4*)(Kbh + (size_t)srow * HDIM + sce);
      uint4 v0 = *(const uint4*)(Vbh + (size_t)srow * SEQL + sce);
      *(uint4*)(&Ks[0][swz(srow, sce)]) = k0;
      *(uint4*)(&Vs[0][swz(srow, sce)]) = v0;
    }
    __syncthreads();

    for (int t = 0; t < NT; ++t) {
      const int cur = t & 1;
      const int kv0 = t * 64;
      const bool pf = (t + 1 < NT);
      uint4 k0, v0;
      if (pf) {  // issue next-tile loads early (T14)
        const int kvn = kv0 + 64;
        k0 = *(const uint4*)(Kbh + (size_t)(kvn + srow) * HDIM + sce);
        v0 = *(const uint4*)(Vbh + (size_t)srow * SEQL + kvn + sce);
      }

      // S^T = K Q^T : lane holds S[kv = kv0 + kb*16 + g*4 + r][q = qrow]
      f32x4 sacc[4];
      __builtin_amdgcn_s_setprio(1);
#pragma unroll
      for (int kb = 0; kb < 4; ++kb) {
        bf16x8 kfa = *(const bf16x8*)(&Ks[cur][swz(kb * 16 + lrow, kg)]);
        bf16x8 kfb = *(const bf16x8*)(&Ks[cur][swz(kb * 16 + lrow, 32 + kg)]);
        f32x4 z = fzero;
        z = __builtin_amdgcn_mfma_f32_16x16x32_bf16(kfa, qf0, z, 0, 0, 0);
        z = __builtin_amdgcn_mfma_f32_16x16x32_bf16(kfb, qf1, z, 0, 0, 0);
        sacc[kb] = z;
      }
      __builtin_amdgcn_s_setprio(0);

      if (kv0 + 63 > q0 + wid * 16) {  // causal mask (diagonal-overlap tiles)
#pragma unroll
        for (int kb = 0; kb < 4; ++kb)
#pragma unroll
          for (int r = 0; r < 4; ++r)
            if (kv0 + kb * 16 + g * 4 + r > qrow) sacc[kb][r] = -1e30f;
      }

      // online softmax in exp2 domain; defer-max (T13)
      float mx = sacc[0][0];
#pragma unroll
      for (int kb = 0; kb < 4; ++kb)
#pragma unroll
        for (int r = 0; r < 4; ++r) mx = fmaxf(mx, sacc[kb][r]);
      mx = fmaxf(mx, __shfl_xor(mx, 16));
      mx = fmaxf(mx, __shfl_xor(mx, 32));

      if (!__all(mx <= m_run + 8.f)) {
        const float mnew = fmaxf(m_run, mx);
        const float sc = __builtin_amdgcn_exp2f(m_run - mnew);
        m_run = mnew;
        l_run *= sc;
#pragma unroll
        for (int d = 0; d < 4; ++d) accO[d] *= sc;
      }

      bf16x8 pa[2];
      float ls = 0.f;
#pragma unroll
      for (int kb = 0; kb < 4; ++kb)
#pragma unroll
        for (int r = 0; r < 4; ++r) {
          float p = __builtin_amdgcn_exp2f(sacc[kb][r] - m_run);
          ls += p;
          pa[kb >> 1][(kb & 1) * 4 + r] = (__bf16)p;
        }
      l_run += ls;

      // PV: mfma(V^T rows, P) -> lane holds O[q=lrow][d = d*16 + g*4 + r]
      __builtin_amdgcn_s_setprio(1);
#pragma unroll
      for (int ks = 0; ks < 2; ++ks)
#pragma unroll
        for (int d = 0; d < 4; ++d) {
          union { ushort4 h2[2]; bf16x8 v; } vf;
          vf.h2[0] = *(const ushort4*)(&Vs[cur][swz(d * 16 + lrow, ks * 32 + g * 4)]);
          vf.h2[1] = *(const ushort4*)(&Vs[cur][swz(d * 16 + lrow, ks * 32 + 16 + g * 4)]);
          accO[d] = __builtin_amdgcn_mfma_f32_16x16x32_bf16(vf.v, pa[ks], accO[d], 0, 0, 0);
        }
      __builtin_amdgcn_s_setprio(0);

      if (pf) {
        const int nb = cur ^ 1;
        *(uint4*)(&Ks[nb][swz(srow, sce)]) = k0;
        *(uint4*)(&Vs[nb][swz(srow, sce)]) = v0;
      }
      __syncthreads();
    }

    float l = l_run;
    l += __shfl_xor(l, 16);
    l += __shfl_xor(l, 32);
    const float inv = 1.f / l;
#pragma unroll
    for (int d = 0; d < 4; ++d) {
      union { u16 s4[4]; uint2 u; } o;
#pragma unroll
      for (int r = 0; r < 4; ++r) o.s4[r] = f2bf(accO[d][r] * inv);
      *(uint2*)(Ab + (size_t)(b * SEQL + qrow) * EMB + h * HDIM + d * 16 + g * 4) = o.u;
    }
    __syncthreads();  // LDS reuse guard before next phase
  }
}

extern "C" void kernel_launch(void* const* d_in, const int* in_sizes, int n_in,
                              void* d_out, int out_size, void* d_ws, size_t ws_size,
                              hipStream_t stream) {
  (void)in_sizes; (void)n_in; (void)out_size; (void)ws_size;
  const float* query = (const float*)d_in[0];
  const float* Wq = (const float*)d_in[1];
  const float* bq = (const float*)d_in[2];
  const float* Wk = (const float*)d_in[3];
  const float* bk = (const float*)d_in[4];
  const float* Wv = (const float*)d_in[5];
  const float* bv = (const float*)d_in[6];
  const float* Wo = (const float*)d_in[7];
  const float* bo = (const float*)d_in[8];
  float* out = (float*)d_out;

  const size_t MB = 1u << 20;
  char* ws = (char*)d_ws;
  u16* Xb  = (u16*)(ws);              // 16 MB (reused as attn output)
  u16* Wqb = (u16*)(ws + 16 * MB);    // Wq,Wk,Wv,Wo contiguous (2 MB each) -> Wcat
  u16* Wob = (u16*)(ws + 22 * MB);
  u16* Qbf = (u16*)(ws + 24 * MB);    // [bh][s][d] bf16
  u16* Kbf = (u16*)(ws + 40 * MB);    // [bh][s][d] bf16
  u16* Vtg = (u16*)(ws + 56 * MB);    // [bh][d][s] bf16 (transposed)
  u16* Ab  = Xb;

  cvt_all<<<6144, 256, 0, stream>>>(query, Wq, Wk, Wv, Wo, Xb, Wqb);
  gemm_qkv3<<<768, 512, 0, stream>>>(Xb, Wqb, bq, bk, bv, Qbf, Kbf, Vtg);
  attn6_kernel<<<512, 512, 0, stream>>>(Qbf, Kbf, Vtg, Ab);
  gemm_out2<<<256, 512, 0, stream>>>(Ab, Wob, bo, out);
}

// Round 15
// 158.879 us; speedup vs baseline: 3.3438x; 3.3438x over previous
//
#include <hip/hip_runtime.h>
#include <stdint.h>

typedef unsigned short u16;
typedef __attribute__((ext_vector_type(8))) __bf16 bf16x8;
typedef __attribute__((ext_vector_type(4))) float f32x4;

#define SEQL 2048
#define NHEADS 16
#define HDIM 64
#define BSZ 4
#define EMB 1024
#define MROWS (BSZ * SEQL) /* 8192 */
#define LOG2E 1.44269504088896f
#define NKT 32 /* K tiles of 32 over K=1024 */

__device__ __forceinline__ u16 f2bf(float f) {
  union { float f; uint32_t u; } v; v.f = f;
  return (u16)((v.u + 0x7fffu + ((v.u >> 16) & 1u)) >> 16);
}

__device__ __forceinline__ void g2l(const u16* g, u16* l) {
  __builtin_amdgcn_global_load_lds(
      (__attribute__((address_space(1))) void*)(g),
      (__attribute__((address_space(3))) void*)(l), 16, 0, 0);
}

__device__ __forceinline__ void cvt8(const float* __restrict__ in, u16* __restrict__ out, int i) {
  float4 a = *(const float4*)(in + i);
  float4 b = *(const float4*)(in + i + 4);
  uint4 o;
  o.x = f2bf(a.x) | ((uint32_t)f2bf(a.y) << 16);
  o.y = f2bf(a.z) | ((uint32_t)f2bf(a.w) << 16);
  o.z = f2bf(b.x) | ((uint32_t)f2bf(b.y) << 16);
  o.w = f2bf(b.z) | ((uint32_t)f2bf(b.w) << 16);
  *(uint4*)(out + i) = o;
}

// ---------------- fused fp32 -> bf16 conversion (X + all 4 weights) ----------------
#define XN (MROWS * EMB)
__global__ void cvt_all(const float* __restrict__ query,
                        const float* __restrict__ w0, const float* __restrict__ w1,
                        const float* __restrict__ w2, const float* __restrict__ w3,
                        u16* __restrict__ Xb, u16* __restrict__ Wqb) {
  int i = (blockIdx.x * blockDim.x + threadIdx.x) * 8;
  if (i < XN) {
    cvt8(query, Xb, i);
  } else {
    int j = i - XN;
    int w = j >> 20;
    int jj = j & 1048575;
    const float* src = w == 0 ? w0 : w == 1 ? w1 : w == 2 ? w2 : w3;
    cvt8(src, Wqb + ((size_t)w << 20), jj);
  }
}

// ============ GEMM core: C[128x256] = A[128xK] * B[256xK]^T, K=1024 (R8 proven) ==
// BK=32, 512 threads (8 waves, 2M x 4N, wave-tile 64x64), 3-deep LDS ring (72 KB),
// counted vmcnt (T4): per iter wait vmcnt(3), raw s_barrier (no vmcnt(0) drain),
// then issue kt+2 into the ring slot whose readers finished before the PREVIOUS
// barrier (race-free). NOTE (R12/R14 lesson): never tighten __launch_bounds__
// below (512,4) on this body — VGPR cap < need => spill storm (40 VGPR, 1.2 GB
// scratch traffic, 6x slowdown).
#define GBODY3(WSTR, RBUF, DOPF, PFT, WBUF)                                         \
  {                                                                                 \
    asm volatile("s_waitcnt " WSTR ::: "memory");                                   \
    __builtin_amdgcn_sched_barrier(0);                                              \
    __builtin_amdgcn_s_barrier();                                                   \
    __builtin_amdgcn_sched_barrier(0);                                              \
    if (DOPF) {                                                                     \
      u16* d = lds + (WBUF) * 12288;                                                \
      g2l(Agb + (PFT) * 32, d + tid * 8);                                           \
      g2l(Bgb0 + (PFT) * 32, d + 4096 + tid * 8);                                   \
      g2l(Bgb1 + (PFT) * 32, d + 8192 + tid * 8);                                   \
    }                                                                               \
    const u16* Ab = lds + (RBUF) * 12288;                                           \
    const u16* Bb = Ab + 4096;                                                      \
    bf16x8 af[4], bfr[4];                                                           \
    _Pragma("unroll") for (int i = 0; i < 4; ++i) {                                 \
      af[i] = *(const bf16x8*)(Ab + (wr * 64 + i * 16 + lrow) * 32 + kg);           \
      bfr[i] = *(const bf16x8*)(Bb + (wc * 64 + i * 16 + lrow) * 32 + kg);          \
    }                                                                               \
    __builtin_amdgcn_s_setprio(1);                                                  \
    _Pragma("unroll") for (int mi = 0; mi < 4; ++mi)                                \
      _Pragma("unroll") for (int ni = 0; ni < 4; ++ni)                              \
        acc[mi][ni] =                                                               \
            __builtin_amdgcn_mfma_f32_16x16x32_bf16(af[mi], bfr[ni], acc[mi][ni],   \
                                                    0, 0, 0);                       \
    __builtin_amdgcn_s_setprio(0);                                                  \
  }

__device__ __forceinline__ void gemm_core256(const u16* __restrict__ A,
                                             const u16* __restrict__ B,
                                             int m0, int n0, u16* lds,
                                             f32x4 acc[4][4]) {
  const int tid = threadIdx.x;
  const int lane = tid & 63, wid = tid >> 6;
  const int wr = wid >> 2, wc = wid & 3;
  const int lrow = lane & 15, kg = (lane >> 4) * 8;
  const int srow = tid >> 2, scolE = (tid & 3) * 8;

  const u16* Agb  = A + (size_t)(m0 + srow) * EMB + scolE;
  const u16* Bgb0 = B + (size_t)(n0 + srow) * EMB + scolE;
  const u16* Bgb1 = B + (size_t)(n0 + 128 + srow) * EMB + scolE;

#pragma unroll
  for (int t = 0; t < 2; ++t) {
    u16* d = lds + t * 12288;
    g2l(Agb + t * 32, d + tid * 8);
    g2l(Bgb0 + t * 32, d + 4096 + tid * 8);
    g2l(Bgb1 + t * 32, d + 8192 + tid * 8);
  }

  int rb = 0;
#pragma unroll 1
  for (int kt = 0; kt < NKT - 2; ++kt) {
    int wb = rb + 2; if (wb >= 3) wb -= 3;
    GBODY3("vmcnt(3)", rb, true, kt + 2, wb)
    ++rb; if (rb == 3) rb = 0;
  }
  GBODY3("vmcnt(3)", rb, false, 0, 0)
  { int rb2 = rb + 1; if (rb2 == 3) rb2 = 0;
    GBODY3("vmcnt(0)", rb2, false, 0, 0) }
}

// Fused QKV projection (R8 proven). Grid 768.
__global__ __launch_bounds__(512, 4) void gemm_qkv3(
    const u16* __restrict__ X, const u16* __restrict__ Wcat,
    const float* __restrict__ bq, const float* __restrict__ bk, const float* __restrict__ bv,
    u16* __restrict__ Qb, u16* __restrict__ Kb, u16* __restrict__ Vt) {
  __shared__ u16 lds[3 * 12288];
  const int orig = blockIdx.x;
  const int virt = (orig & 7) * 96 + (orig >> 3);
  const int mt = virt / 12, nt = virt % 12;

  const f32x4 fzero = {0.f, 0.f, 0.f, 0.f};
  f32x4 acc[4][4];
#pragma unroll
  for (int i = 0; i < 4; ++i)
#pragma unroll
    for (int j = 0; j < 4; ++j) acc[i][j] = fzero;

  gemm_core256(X, Wcat, mt * 128, nt * 256, lds, acc);

  const int tid = threadIdx.x, lane = tid & 63, wid = tid >> 6;
  const int wr = wid >> 2, wc = wid & 3;
  const int lrow = lane & 15, g = lane >> 4;
  const int which = nt >> 2;
  const float* bias = which == 0 ? bq : which == 1 ? bk : bv;
  const float scale = which == 0 ? 0.125f * LOG2E : 1.0f;

  if (which == 2) {
#pragma unroll
    for (int mi = 0; mi < 4; ++mi)
#pragma unroll
      for (int ni = 0; ni < 4; ++ni) {
        int n = nt * 256 + wc * 64 + ni * 16 + lrow;
        int nn = n & 1023;
        float bs = bias[nn];
        int h = nn >> 6, d = nn & 63;
        int m0r = mt * 128 + wr * 64 + mi * 16 + g * 4;
        int b = m0r >> 11, s = m0r & 2047;
        union { u16 s4[4]; uint2 u; } o;
#pragma unroll
        for (int r = 0; r < 4; ++r) o.s4[r] = f2bf(acc[mi][ni][r] + bs);
        *(uint2*)(Vt + ((size_t)(b * NHEADS + h) * HDIM + d) * SEQL + s) = o.u;
      }
  } else {
    u16* Ob = which == 0 ? Qb : Kb;
#pragma unroll
    for (int mi = 0; mi < 4; ++mi)
#pragma unroll
      for (int ni = 0; ni < 4; ++ni) {
        int n = nt * 256 + wc * 64 + ni * 16 + lrow;
        int nn = n & 1023;
        float bs = bias[nn];
        int h = nn >> 6, d = nn & 63;
#pragma unroll
        for (int r = 0; r < 4; ++r) {
          int m = mt * 128 + wr * 64 + mi * 16 + g * 4 + r;
          int b = m >> 11, s = m & 2047;
          float v = (acc[mi][ni][r] + bs) * scale;
          Ob[(size_t)((b * NHEADS + h) * SEQL + s) * HDIM + d] = f2bf(v);
        }
      }
  }
}

// Output projection (R8 proven). Grid 256.
__global__ __launch_bounds__(512, 4) void gemm_out2(
    const u16* __restrict__ Ain, const u16* __restrict__ Wo,
    const float* __restrict__ bo, float* __restrict__ out) {
  __shared__ u16 lds[3 * 12288];
  const int orig = blockIdx.x;
  const int virt = (orig & 7) * 32 + (orig >> 3);
  const int mt = virt >> 2, nt = virt & 3;

  const f32x4 fzero = {0.f, 0.f, 0.f, 0.f};
  f32x4 acc[4][4];
#pragma unroll
  for (int i = 0; i < 4; ++i)
#pragma unroll
    for (int j = 0; j < 4; ++j) acc[i][j] = fzero;

  gemm_core256(Ain, Wo, mt * 128, nt * 256, lds, acc);

  const int tid = threadIdx.x, lane = tid & 63, wid = tid >> 6;
  const int wr = wid >> 2, wc = wid & 3;
  const int lrow = lane & 15, g = lane >> 4;
#pragma unroll
  for (int mi = 0; mi < 4; ++mi)
#pragma unroll
    for (int ni = 0; ni < 4; ++ni) {
      int n = nt * 256 + wc * 64 + ni * 16 + lrow;
      float bs = bo[n];
#pragma unroll
      for (int r = 0; r < 4; ++r) {
        int m = mt * 128 + wr * 64 + mi * 16 + g * 4 + r;
        out[(size_t)m * EMB + n] = acc[mi][ni][r] + bs;
      }
    }
}

// ---------------- causal flash attention (R11's proven attn6, 74.9 us) -----------
// QBLK=128, 512 threads, shared K/V staging, pair-balanced {qa, 15-qa} -> 34
// uniform KV-iters/block, grid 512. Swapped QK^T (in-reg P), exp2 softmax,
// defer-max (T13), XOR-swizzled LDS, setprio MFMA clusters, dbuf + reg-prefetch.
__device__ __forceinline__ int swz(int row, int colE) {
  return row * 64 + (colE ^ ((row & 7) << 3));
}

__global__ __launch_bounds__(512, 4) void attn6_kernel(
    const u16* __restrict__ Qb, const u16* __restrict__ Kb, const u16* __restrict__ Vt,
    u16* __restrict__ Ab) {
  __shared__ u16 Ks[2][64 * 64];
  __shared__ u16 Vs[2][64 * 64];

  const int bid = blockIdx.x;
  const int qa  = bid >> 6;          // 0..7
  const int bh  = bid & 63;

  const int tid = threadIdx.x, lane = tid & 63, wid = tid >> 6;  // wid 0..7
  const int lrow = lane & 15, g = lane >> 4, kg = g * 8;

  const u16* Qbh = Qb + (size_t)bh * SEQL * HDIM;
  const u16* Kbh = Kb + (size_t)bh * SEQL * HDIM;
  const u16* Vbh = Vt + (size_t)bh * HDIM * SEQL;

  const int srow = tid >> 3;            // 0..63 (full tile, one load/thread)
  const int sce  = (tid & 7) * 8;

  const f32x4 fzero = {0.f, 0.f, 0.f, 0.f};
  const int b = bh >> 4, h = bh & 15;

#pragma unroll 1
  for (int ph = 0; ph < 2; ++ph) {
    const int qt = ph ? (15 - qa) : qa;      // q-tile of 128 rows
    const int q0 = qt * 128;
    const int NT = 2 * (qt + 1);             // 64-wide kv tiles

    const int qrow = q0 + wid * 16 + lrow;
    const bf16x8 qf0 = *(const bf16x8*)(Qbh + (size_t)qrow * HDIM + kg);
    const bf16x8 qf1 = *(const bf16x8*)(Qbh + (size_t)qrow * HDIM + 32 + kg);

    float m_run = -1e30f, l_run = 0.f;
    f32x4 accO[4];
#pragma unroll
    for (int d = 0; d < 4; ++d) accO[d] = fzero;

    // prologue: stage tile 0 (1 K + 1 V uint4 per thread)
    {
      uint4 k0 = *(const uint4*)(Kbh + (size_t)srow * HDIM + sce);
      uint4 v0 = *(const uint4*)(Vbh + (size_t)srow * SEQL + sce);
      *(uint4*)(&Ks[0][swz(srow, sce)]) = k0;
      *(uint4*)(&Vs[0][swz(srow, sce)]) = v0;
    }
    __syncthreads();

    for (int t = 0; t < NT; ++t) {
      const int cur = t & 1;
      const int kv0 = t * 64;
      const bool pf = (t + 1 < NT);
      uint4 k0, v0;
      if (pf) {  // issue next-tile loads early (T14)
        const int kvn = kv0 + 64;
        k0 = *(const uint4*)(Kbh + (size_t)(kvn + srow) * HDIM + sce);
        v0 = *(const uint4*)(Vbh + (size_t)srow * SEQL + kvn + sce);
      }

      // S^T = K Q^T : lane holds S[kv = kv0 + kb*16 + g*4 + r][q = qrow]
      f32x4 sacc[4];
      __builtin_amdgcn_s_setprio(1);
#pragma unroll
      for (int kb = 0; kb < 4; ++kb) {
        bf16x8 kfa = *(const bf16x8*)(&Ks[cur][swz(kb * 16 + lrow, kg)]);
        bf16x8 kfb = *(const bf16x8*)(&Ks[cur][swz(kb * 16 + lrow, 32 + kg)]);
        f32x4 z = fzero;
        z = __builtin_amdgcn_mfma_f32_16x16x32_bf16(kfa, qf0, z, 0, 0, 0);
        z = __builtin_amdgcn_mfma_f32_16x16x32_bf16(kfb, qf1, z, 0, 0, 0);
        sacc[kb] = z;
      }
      __builtin_amdgcn_s_setprio(0);

      if (kv0 + 63 > q0 + wid * 16) {  // causal mask (diagonal-overlap tiles)
#pragma unroll
        for (int kb = 0; kb < 4; ++kb)
#pragma unroll
          for (int r = 0; r < 4; ++r)
            if (kv0 + kb * 16 + g * 4 + r > qrow) sacc[kb][r] = -1e30f;
      }

      // online softmax in exp2 domain; defer-max (T13)
      float mx = sacc[0][0];
#pragma unroll
      for (int kb = 0; kb < 4; ++kb)
#pragma unroll
        for (int r = 0; r < 4; ++r) mx = fmaxf(mx, sacc[kb][r]);
      mx = fmaxf(mx, __shfl_xor(mx, 16));
      mx = fmaxf(mx, __shfl_xor(mx, 32));

      if (!__all(mx <= m_run + 8.f)) {
        const float mnew = fmaxf(m_run, mx);
        const float sc = __builtin_amdgcn_exp2f(m_run - mnew);
        m_run = mnew;
        l_run *= sc;
#pragma unroll
        for (int d = 0; d < 4; ++d) accO[d] *= sc;
      }

      bf16x8 pa[2];
      float ls = 0.f;
#pragma unroll
      for (int kb = 0; kb < 4; ++kb)
#pragma unroll
        for (int r = 0; r < 4; ++r) {
          float p = __builtin_amdgcn_exp2f(sacc[kb][r] - m_run);
          ls += p;
          pa[kb >> 1][(kb & 1) * 4 + r] = (__bf16)p;
        }
      l_run += ls;

      // PV: mfma(V^T rows, P) -> lane holds O[q=lrow][d = d*16 + g*4 + r]
      __builtin_amdgcn_s_setprio(1);
#pragma unroll
      for (int ks = 0; ks < 2; ++ks)
#pragma unroll
        for (int d = 0; d < 4; ++d) {
          union { ushort4 h2[2]; bf16x8 v; } vf;
          vf.h2[0] = *(const ushort4*)(&Vs[cur][swz(d * 16 + lrow, ks * 32 + g * 4)]);
          vf.h2[1] = *(const ushort4*)(&Vs[cur][swz(d * 16 + lrow, ks * 32 + 16 + g * 4)]);
          accO[d] = __builtin_amdgcn_mfma_f32_16x16x32_bf16(vf.v, pa[ks], accO[d], 0, 0, 0);
        }
      __builtin_amdgcn_s_setprio(0);

      if (pf) {
        const int nb = cur ^ 1;
        *(uint4*)(&Ks[nb][swz(srow, sce)]) = k0;
        *(uint4*)(&Vs[nb][swz(srow, sce)]) = v0;
      }
      __syncthreads();
    }

    float l = l_run;
    l += __shfl_xor(l, 16);
    l += __shfl_xor(l, 32);
    const float inv = 1.f / l;
#pragma unroll
    for (int d = 0; d < 4; ++d) {
      union { u16 s4[4]; uint2 u; } o;
#pragma unroll
      for (int r = 0; r < 4; ++r) o.s4[r] = f2bf(accO[d][r] * inv);
      *(uint2*)(Ab + (size_t)(b * SEQL + qrow) * EMB + h * HDIM + d * 16 + g * 4) = o.u;
    }
    __syncthreads();  // LDS reuse guard before next phase
  }
}

extern "C" void kernel_launch(void* const* d_in, const int* in_sizes, int n_in,
                              void* d_out, int out_size, void* d_ws, size_t ws_size,
                              hipStream_t stream) {
  (void)in_sizes; (void)n_in; (void)out_size; (void)ws_size;
  const float* query = (const float*)d_in[0];
  const float* Wq = (const float*)d_in[1];
  const float* bq = (const float*)d_in[2];
  const float* Wk = (const float*)d_in[3];
  const float* bk = (const float*)d_in[4];
  const float* Wv = (const float*)d_in[5];
  const float* bv = (const float*)d_in[6];
  const float* Wo = (const float*)d_in[7];
  const float* bo = (const float*)d_in[8];
  float* out = (float*)d_out;

  const size_t MB = 1u << 20;
  char* ws = (char*)d_ws;
  u16* Xb  = (u16*)(ws);              // 16 MB (reused as attn output)
  u16* Wqb = (u16*)(ws + 16 * MB);    // Wq,Wk,Wv,Wo contiguous (2 MB each) -> Wcat
  u16* Wob = (u16*)(ws + 22 * MB);
  u16* Qbf = (u16*)(ws + 24 * MB);    // [bh][s][d] bf16
  u16* Kbf = (u16*)(ws + 40 * MB);    // [bh][s][d] bf16
  u16* Vtg = (u16*)(ws + 56 * MB);    // [bh][d][s] bf16 (transposed)
  u16* Ab  = Xb;

  cvt_all<<<6144, 256, 0, stream>>>(query, Wq, Wk, Wv, Wo, Xb, Wqb);
  gemm_qkv3<<<768, 512, 0, stream>>>(Xb, Wqb, bq, bk, bv, Qbf, Kbf, Vtg);
  attn6_kernel<<<512, 512, 0, stream>>>(Qbf, Kbf, Vtg, Ab);
  gemm_out2<<<256, 512, 0, stream>>>(Ab, Wob, bo, out);
}